// Round 1
// baseline (672.461 us; speedup 1.0000x reference)
//
#include <hip/hip_runtime.h>

#define B_ 2048
#define T_ 2048

__device__ __forceinline__ float lane_bcast(float v, int lane) {
    return __builtin_bit_cast(float, __builtin_amdgcn_readlane(__builtin_bit_cast(int, v), lane));
}

// Single-instruction DPP permute on f32, bound_ctrl=1 (no invalid lanes under
// full exec for our patterns: quad_perm / half_mirror / mirror).
template <int CTRL>
__device__ __forceinline__ float dppf(float v) {
    return __builtin_bit_cast(float,
        (unsigned)__builtin_amdgcn_update_dpp(0, (int)__builtin_bit_cast(unsigned, v),
                                              CTRL, 0xF, 0xF, true));
}

// Raw bpermute with hoisted byte-address. dst[l] = src[addr[l]>>2].
__device__ __forceinline__ float bperm(int addr, float v) {
    return __builtin_bit_cast(float,
        __builtin_amdgcn_ds_bpermute(addr, __builtin_bit_cast(int, v)));
}

// ZERO-LDS recurrence, f32 datapath (round-12: moved off the f16 dot pipe).
// Lane l owns h[l]. Per step:
//  1) 15-instr DPP all-gather of the lane's 16-group h values in f32.
//     hv[s] = h[l^s]; xor masks composed from quad_perm(1,2,3),
//     row_half_mirror(7), row_mirror(15):  s^7 and s^15 compositions.
//  2) 4 partial-dot chains (rows l, l^16, l^32, l^48; k-grp l>>4),
//     65x v_fmac_f32 (full-rate pipe; v_dot2_f32_f16 measured multi-cycle).
//     a1/a2/a3 computed FIRST so the 3 bpermutes issue early and their DS
//     latency hides under chain-0's FMA chain.
//  3) y = (a0+a0b) + bperm(a1,l^16) + bperm(a2,l^32) + bperm(a3,l^48)
//  4) tanh via exp2 (2*log2e folded into W/bias at init).
__global__ __launch_bounds__(64)
__attribute__((amdgpu_waves_per_eu(2, 2)))
void rnn_dpp4(
    const float* __restrict__ x, const float* __restrict__ W_ih,
    const float* __restrict__ W_hh, const float* __restrict__ b_ih,
    const float* __restrict__ b_hh, const float* __restrict__ W_fc,
    const float* __restrict__ b_fc, float* __restrict__ out)
{
    const int b = blockIdx.x;
    const int l = threadIdx.x;
    const float L2E2 = 2.8853900817779268f;  // 2*log2(e), folded into W/bias

    // Per-lane weight registers: chain c covers output row (l ^ (c<<4)),
    // slot s covers k = (l&48) | ((l&15)^s)  (matches the DPP gather order).
    float w0[16], w1[16], w2[16], w3[16];
#pragma unroll
    for (int s = 0; s < 16; ++s) {
        const int k = (l & 48) | ((l & 15) ^ s);
        w0[s] = W_hh[(l      ) * 64 + k] * L2E2;
        w1[s] = W_hh[(l ^ 16) * 64 + k] * L2E2;
        w2[s] = W_hh[(l ^ 32) * 64 + k] * L2E2;
        w3[s] = W_hh[(l ^ 48) * 64 + k] * L2E2;
    }

    const float wih  = W_ih[l] * L2E2;             // row l's input weight
    const float bias = (b_ih[l] + b_hh[l]) * L2E2; // row l's bias (enters once, chain 0)

    // Loop-invariant bpermute byte-addresses.
    const int ax16 = (l ^ 16) << 2;
    const int ax32 = (l ^ 32) << 2;
    const int ax48 = (l ^ 48) << 2;

    float h = 0.0f;  // h0 = 0; lane l owns h[l]
    const float* xb = x + (size_t)b * T_;
    float xr = xb[l];

    for (int t0 = 0; t0 < T_; t0 += 64) {
        const int ni = t0 + 64 + l;
        const float xn = xb[ni < T_ ? ni : 0];  // next-chunk prefetch

#pragma unroll 2
        for (int tt = 0; tt < 64; ++tt) {
            // --- 1) DPP all-gather, f32 (15 instrs, depth <= 3) ---
            float hv[16];
            hv[0]  = h;
            hv[1]  = dppf<0xB1>(h);     // quad_perm [1,0,3,2] -> l^1
            hv[2]  = dppf<0x4E>(h);     // quad_perm [2,3,0,1] -> l^2
            hv[3]  = dppf<0x1B>(h);     // quad_perm [3,2,1,0] -> l^3
            hv[7]  = dppf<0x141>(h);    // row_half_mirror     -> l^7
            hv[15] = dppf<0x140>(h);    // row_mirror          -> l^15
            hv[4]  = dppf<0x141>(hv[3]);   // (l^3)^7  = l^4
            hv[5]  = dppf<0x141>(hv[2]);   // (l^2)^7  = l^5
            hv[6]  = dppf<0x141>(hv[1]);   // (l^1)^7  = l^6
            hv[8]  = dppf<0x140>(hv[7]);   // (l^7)^15 = l^8
            hv[9]  = dppf<0x140>(hv[6]);   // (l^6)^15 = l^9
            hv[10] = dppf<0x140>(hv[5]);   // l^10
            hv[11] = dppf<0x140>(hv[4]);   // l^11
            hv[12] = dppf<0x140>(hv[3]);   // l^12
            hv[13] = dppf<0x140>(hv[2]);   // l^13
            hv[14] = dppf<0x140>(hv[1]);   // l^14

            // --- 2a) cross-row chains first (rows l^16, l^32, l^48) ---
            float a1 = 0.0f, a2 = 0.0f, a3 = 0.0f;
#pragma unroll
            for (int s = 0; s < 16; ++s) {
                a1 = fmaf(hv[s], w1[s], a1);
                a2 = fmaf(hv[s], w2[s], a2);
                a3 = fmaf(hv[s], w3[s], a3);
            }
            // --- 3a) issue bpermutes early; latency hides under chain 0 ---
            const float r1 = bperm(ax16, a1);
            const float r2 = bperm(ax32, a2);
            const float r3 = bperm(ax48, a3);

            // --- 2b) own-row chain (row l), split 2-way for ILP ---
            const float xt = lane_bcast(xr, tt);
            float a0  = fmaf(xt, wih, bias);  // affine enters exactly once
            float a0b = 0.0f;
#pragma unroll
            for (int s = 0; s < 8; ++s) {
                a0  = fmaf(hv[2 * s],     w0[2 * s],     a0);
                a0b = fmaf(hv[2 * s + 1], w0[2 * s + 1], a0b);
            }

            // --- 3b) reduce ---
            const float y = (a0 + a0b) + ((r1 + r2) + r3);

            // --- 4) tanh(pre) = 1 - 2/(exp2(2log2e*pre)+1) ---
            const float e = __builtin_amdgcn_exp2f(y);
            h = fmaf(-2.0f, __builtin_amdgcn_rcpf(e + 1.0f), 1.0f);
        }
        xr = xn;
    }

    // out[b] = dot(h_last, W_fc[0,:]) + b_fc[0] -- one wave reduction.
    float p = h * W_fc[l];
#pragma unroll
    for (int off = 32; off > 0; off >>= 1) p += __shfl_down(p, off);
    if (l == 0) out[b] = p + b_fc[0];
}

extern "C" void kernel_launch(void* const* d_in, const int* in_sizes, int n_in,
                              void* d_out, int out_size, void* d_ws, size_t ws_size,
                              hipStream_t stream) {
    const float* x    = (const float*)d_in[0];
    const float* W_ih = (const float*)d_in[1];
    const float* W_hh = (const float*)d_in[2];
    const float* b_ih = (const float*)d_in[3];
    const float* b_hh = (const float*)d_in[4];
    const float* W_fc = (const float*)d_in[5];
    const float* b_fc = (const float*)d_in[6];
    float* out = (float*)d_out;

    rnn_dpp4<<<dim3(B_), dim3(64), 0, stream>>>(x, W_ih, W_hh, b_ih, b_hh, W_fc, b_fc, out);
}